// Round 1
// baseline (13.802 us; speedup 1.0000x reference)
//
#include <hip/hip_runtime.h>

// NeuS renderer: per-ray alpha compositing over D=128 depth samples.
// sdf_grid:   (B, D, H, W)    float32
// color_grid: (B, 3, D, H, W) float32
// variance:   scalar float32
// out: color (B,3,H,W) flat, then weights_sum (B,1,H,W) flat.
//
// One thread per ray (b,h,w). For fixed d, consecutive threads (consecutive w)
// hit consecutive addresses -> fully coalesced despite the per-thread d-stride.
// Early exit when transmittance < 1e-6: remaining weight mass (and color, in
// [0,1]) is bounded by trans, so truncation error <= 1e-6 << 2e-2 threshold.

#define BB 2
#define DD 128
#define HH 256
#define WW 256

__global__ __launch_bounds__(256) void neus_render_kernel(
    const float* __restrict__ sdf_grid,
    const float* __restrict__ color_grid,
    const float* __restrict__ variance,
    float* __restrict__ out)
{
    const int NHW = HH * WW;                       // 65536
    const int idx = blockIdx.x * blockDim.x + threadIdx.x;
    if (idx >= BB * NHW) return;
    const int b  = idx / NHW;
    const int hw = idx - b * NHW;

    const float inv_s = __expf(variance[0] * 10.0f);

    const size_t dstride = (size_t)NHW;            // stride between depth samples
    const size_t cstride = (size_t)DD * NHW;       // stride between color channels

    const float* __restrict__ sdf = sdf_grid   + (size_t)b * DD * NHW + hw;
    const float* __restrict__ col = color_grid + (size_t)b * 3 * DD * NHW + hw;

    float trans = 1.0f;
    float c0 = 0.0f, c1 = 0.0f, c2 = 0.0f, wsum = 0.0f;

    float s0 = sdf[0];
    float prev_cdf = 1.0f / (1.0f + __expf(-s0 * inv_s));

    for (int d = 0; d < DD - 1; ++d) {
        float sn = sdf[(size_t)(d + 1) * dstride];
        float next_cdf = 1.0f / (1.0f + __expf(-sn * inv_s));
        float alpha = (prev_cdf - next_cdf + 1e-5f) / (prev_cdf + 1e-5f);
        alpha = fminf(fmaxf(alpha, 0.0f), 1.0f);
        float w = alpha * trans;
        wsum += w;
        c0 += col[(size_t)d * dstride] * w;
        c1 += col[cstride + (size_t)d * dstride] * w;
        c2 += col[2 * cstride + (size_t)d * dstride] * w;
        trans *= (1.0f - alpha + 1e-7f);
        prev_cdf = next_cdf;
        if (trans < 1e-6f) break;   // bounded truncation error <= 1e-6
    }

    // Outputs: color (B,3,H,W) then weights_sum (B,1,H,W), concatenated flat.
    out[((size_t)b * 3 + 0) * NHW + hw] = c0;
    out[((size_t)b * 3 + 1) * NHW + hw] = c1;
    out[((size_t)b * 3 + 2) * NHW + hw] = c2;
    out[(size_t)BB * 3 * NHW + (size_t)b * NHW + hw] = wsum;
}

extern "C" void kernel_launch(void* const* d_in, const int* in_sizes, int n_in,
                              void* d_out, int out_size, void* d_ws, size_t ws_size,
                              hipStream_t stream)
{
    const float* sdf_grid   = (const float*)d_in[0];
    const float* color_grid = (const float*)d_in[1];
    const float* variance   = (const float*)d_in[2];
    float* out = (float*)d_out;

    const int total = BB * HH * WW;                // 131072 rays
    dim3 block(256);
    dim3 grid((total + 255) / 256);                // 512 blocks
    neus_render_kernel<<<grid, block, 0, stream>>>(sdf_grid, color_grid, variance, out);
}